// Round 11
// baseline (380.332 us; speedup 1.0000x reference)
//
#include <hip/hip_runtime.h>

#define NB 32
#define NPTS 1024
#define NP 256
#define NS 16
#define NC 256
#define NH 128
#define NOUT 97
#define RP 16    // main: X-tile row stride (floats); reads are uniform-broadcast
#define RP2 20   // gfeat staging row stride: bank-spread writes

// ---------------------------------------------------------------------------
// Prep.
//   w0l[(c*32+og)*4+k] = sa_w0[og+32k][3+c]        (gfeat: 32 o-groups x 4)
//   wl*[(c*64+m)*2+t]  = W[m+64t][c]               (main: o-pair per lane,
//                                                   dwordx2, fully coalesced)
// ---------------------------------------------------------------------------
__global__ __launch_bounds__(256) void prep_kernel(
    const float* __restrict__ sa_w0, const float* __restrict__ sa_w1,
    const float* __restrict__ sa_w2, const float* __restrict__ fc_w1,
    const float* __restrict__ fc_w2, const float* __restrict__ fc_w3,
    float* __restrict__ w0l, float* __restrict__ w0x,
    float* __restrict__ wl1, float* __restrict__ wl2,
    float* __restrict__ fl1, float* __restrict__ fl2,
    float* __restrict__ fl3)
{
  int t = blockIdx.x * 256 + threadIdx.x;
  if (t >= 256 * 128) return;
  int c = t >> 7, o = t & 127;
  w0l[(c * 32 + (o & 31)) * 4 + (o >> 5)] = sa_w0[o * 259 + 3 + c];
  if (c < 3) w0x[c * 128 + o] = sa_w0[o * 259 + c];
  if (c < 128) {
    int qi = (c * 64 + (o & 63)) * 2 + (o >> 6);
    wl1[qi] = sa_w1[o * 128 + c];
    wl2[qi] = sa_w2[o * 128 + c];
    fl1[qi] = fc_w1[o * 128 + c];
    fl2[qi] = fc_w2[o * 128 + c];
    fl3[qi] = (o < NOUT) ? fc_w3[o * 128 + c] : 0.0f;
  }
}

// DPP reduction ladder steps (16-lane rows): row_shr:1/2/4/8, bcast15, bcast31
template <int CTRL>
__device__ __forceinline__ float dpp_fmax(float v) {
  float o = __int_as_float(
      __builtin_amdgcn_mov_dpp(__float_as_int(v), CTRL, 0xF, 0xF, true));
  return fmaxf(v, o);   // bound_ctrl: invalid lanes -> 0; v >= 0 so identity
}
template <int CTRL>
__device__ __forceinline__ unsigned dpp_umax(unsigned v) {
  unsigned o = (unsigned)__builtin_amdgcn_mov_dpp((int)v, CTRL, 0xF, 0xF, true);
  return v > o ? v : o;
}

// ---------------------------------------------------------------------------
// Fused FPS + gfeat, 64-thread (1-wave) blocks.
//   blocks [0, NB):       FPS at s_setprio(3): latency-critical single wave
//                         must win CU arbitration over co-resident gfeat.
//   blocks [NB, NB+2048): gfeat, j-split-2: acc[4][8], full-c per lane.
// ---------------------------------------------------------------------------
__global__ __launch_bounds__(64) void fused_fps_gfeat_kernel(
    const float* __restrict__ xyz, int* __restrict__ inds,
    const float* __restrict__ features, const float* __restrict__ w0l,
    float* __restrict__ G)
{
  __shared__ __align__(16) float smem[NC * RP2];   // 20 KB
  const int lane = threadIdx.x;

  if (blockIdx.x < NB) {
    // ------------------------- FPS -------------------------
    __builtin_amdgcn_s_setprio(3);
    const int b = blockIdx.x;
    const float* xb = xyz + b * NPTS * 3;
    float* s_x = smem;
    float* s_y = smem + NPTS;
    float* s_z = smem + 2 * NPTS;
    float px[16], py[16], pz[16], dist[16];
    const float4* src = reinterpret_cast<const float4*>(xb + lane * 48);
#pragma unroll
    for (int q = 0; q < 4; ++q) {
      float4 v0 = src[3 * q], v1 = src[3 * q + 1], v2 = src[3 * q + 2];
      const float xv[4] = {v0.x, v0.w, v1.z, v2.y};
      const float yv[4] = {v0.y, v1.x, v1.w, v2.z};
      const float zv[4] = {v0.z, v1.y, v2.x, v2.w};
#pragma unroll
      for (int t = 0; t < 4; ++t) {
        int j = 4 * q + t;
        px[j] = xv[t]; py[j] = yv[t]; pz[j] = zv[t];
        s_x[lane * 16 + j] = xv[t];
        s_y[lane * 16 + j] = yv[t];
        s_z[lane * 16 + j] = zv[t];
      }
    }
#pragma unroll
    for (int j = 0; j < 16; ++j) dist[j] = 1e10f;
    int far = 0;
    for (int i = 0; i < NP; ++i) {
      if (lane == 0) inds[b * NP + i] = far;
      float cx = s_x[far], cy = s_y[far], cz = s_z[far];   // uniform broadcast
#pragma unroll
      for (int j = 0; j < 16; ++j) {
#pragma clang fp contract(off)
        float dx = px[j] - cx;
        float dy = py[j] - cy;
        float dz = pz[j] - cz;
        float d = (dx * dx + dy * dy) + dz * dz;
        dist[j] = fminf(dist[j], d);
      }
      // depth-4 first-max tree over dist[0..15] (left wins ties)
      float v8[8]; int i8[8];
#pragma unroll
      for (int t = 0; t < 8; ++t) {
        bool r = dist[2 * t + 1] > dist[2 * t];
        v8[t] = r ? dist[2 * t + 1] : dist[2 * t];
        i8[t] = r ? 2 * t + 1 : 2 * t;
      }
      float v4[4]; int i4[4];
#pragma unroll
      for (int t = 0; t < 4; ++t) {
        bool r = v8[2 * t + 1] > v8[2 * t];
        v4[t] = r ? v8[2 * t + 1] : v8[2 * t];
        i4[t] = r ? i8[2 * t + 1] : i8[2 * t];
      }
      float v2a, v2b; int i2a, i2b;
      { bool r = v4[1] > v4[0]; v2a = r ? v4[1] : v4[0]; i2a = r ? i4[1] : i4[0]; }
      { bool r = v4[3] > v4[2]; v2b = r ? v4[3] : v4[2]; i2b = r ? i4[3] : i4[2]; }
      float bv; int bi;
      { bool r = v2b > v2a; bv = r ? v2b : v2a; bi = lane * 16 + (r ? i2b : i2a); }
      // global max of bv (pure VALU DPP ladder), lane 63 holds result
      float r = bv;
      r = dpp_fmax<0x111>(r);
      r = dpp_fmax<0x112>(r);
      r = dpp_fmax<0x114>(r);
      r = dpp_fmax<0x118>(r);
      r = dpp_fmax<0x142>(r);
      r = dpp_fmax<0x143>(r);
      float gmax = __int_as_float(__builtin_amdgcn_readlane(__float_as_int(r), 63));
      // first (min-index) lane achieving gmax: max of ~idx among candidates
      unsigned cand = (bv == gmax) ? ~(unsigned)bi : 0u;
      cand = dpp_umax<0x111>(cand);
      cand = dpp_umax<0x112>(cand);
      cand = dpp_umax<0x114>(cand);
      cand = dpp_umax<0x118>(cand);
      cand = dpp_umax<0x142>(cand);
      cand = dpp_umax<0x143>(cand);
      unsigned cmax = (unsigned)__builtin_amdgcn_readlane((int)cand, 63);
      far = (int)(~cmax);
    }
    return;
  }

  // ------------------------- gfeat (j-split-2) -------------------------
  const int blk = blockIdx.x - NB;
  const int b  = blk >> 6;
  const int n0 = (blk & 63) * 16;
  const int og = lane & 31;
  const int jg = lane >> 5;
  const int joff = jg * 8;
  const float* fb = features + b * NC * NPTS;
#pragma unroll
  for (int r = 0; r < 4; ++r) {
    int c = r * 64 + lane;
    const float4* s4 = reinterpret_cast<const float4*>(fb + c * NPTS + n0);
    float4 v0 = s4[0], v1 = s4[1], v2 = s4[2], v3 = s4[3];
    float* row = smem + c * RP2;
    reinterpret_cast<float4*>(row)[0] = v0;
    reinterpret_cast<float4*>(row)[1] = v1;
    reinterpret_cast<float4*>(row)[2] = v2;
    reinterpret_cast<float4*>(row)[3] = v3;
  }
  // single wave: LDS write->read ordered in-wave.
  float acc[4][8];
#pragma unroll
  for (int k = 0; k < 4; ++k)
#pragma unroll
    for (int nn = 0; nn < 8; ++nn) acc[k][nn] = 0.0f;
#pragma unroll 2
  for (int c = 0; c < NC; ++c) {
    const float4 wq = *reinterpret_cast<const float4*>(w0l + (c * 32 + og) * 4);
    const float* row = smem + c * RP2 + joff;
    const float4 xa = reinterpret_cast<const float4*>(row)[0];
    const float4 xb4 = reinterpret_cast<const float4*>(row)[1];
    const float wk[4] = {wq.x, wq.y, wq.z, wq.w};
    const float xr[8] = {xa.x, xa.y, xa.z, xa.w, xb4.x, xb4.y, xb4.z, xb4.w};
#pragma unroll
    for (int k = 0; k < 4; ++k)
#pragma unroll
      for (int nn = 0; nn < 8; ++nn)
        acc[k][nn] = fmaf(wk[k], xr[nn], acc[k][nn]);
  }
#pragma unroll
  for (int k = 0; k < 4; ++k) {
    int o = og + 32 * k;
    float* gp = G + ((size_t)(b * NPTS + n0 + joff)) * NH + o;
#pragma unroll
    for (int nn = 0; nn < 8; ++nn) gp[nn * NH] = acc[k][nn];
  }
}

// 8 FMAs into acc0/acc1 at literal base J from float4 XQ
#define FMA_Q(J, XQ) \
  acc0[(J) + 0] = fmaf(wv.x, (XQ).x, acc0[(J) + 0]); \
  acc1[(J) + 0] = fmaf(wv.y, (XQ).x, acc1[(J) + 0]); \
  acc0[(J) + 1] = fmaf(wv.x, (XQ).y, acc0[(J) + 1]); \
  acc1[(J) + 1] = fmaf(wv.y, (XQ).y, acc1[(J) + 1]); \
  acc0[(J) + 2] = fmaf(wv.x, (XQ).z, acc0[(J) + 2]); \
  acc1[(J) + 2] = fmaf(wv.y, (XQ).z, acc1[(J) + 2]); \
  acc0[(J) + 3] = fmaf(wv.x, (XQ).w, acc0[(J) + 3]); \
  acc1[(J) + 3] = fmaf(wv.y, (XQ).w, acc1[(J) + 3]);

// Full 128-c MLP layer: weights via coalesced dwordx2 (zero redundancy),
// X rows via uniform-address b128 broadcasts (conflict-free).
#define MLP_LAYER(WPTR) \
  _Pragma("unroll") for (int j = 0; j < 16; ++j) { acc0[j] = 0.0f; acc1[j] = 0.0f; } \
  _Pragma("unroll 2") \
  for (int c = 0; c < NH; ++c) { \
    const float2 wv = *reinterpret_cast<const float2*>((WPTR) + (c * 64 + lane) * 2); \
    const float4* rowp = reinterpret_cast<const float4*>(xs + c * RP); \
    const float4 xq0 = rowp[0]; FMA_Q(0, xq0) \
    const float4 xq1 = rowp[1]; FMA_Q(4, xq1) \
    const float4 xq2 = rowp[2]; FMA_Q(8, xq2) \
    const float4 xq3 = rowp[3]; FMA_Q(12, xq3) \
  }

// FC matvec: h0/h1 += W[lane][c]*f[c], W[lane+64][c]*f[c]; f read uniform.
#define FC_LAYER(WPTR, SRCOFF) \
  h0 = 0.0f; h1 = 0.0f; \
  _Pragma("unroll 4") \
  for (int c4 = 0; c4 < 32; ++c4) { \
    const float4 fq = *reinterpret_cast<const float4*>(xs + (SRCOFF) + c4 * 4); \
    { const float2 wv = *reinterpret_cast<const float2*>((WPTR) + ((c4 * 4 + 0) * 64 + lane) * 2); \
      h0 = fmaf(wv.x, fq.x, h0); h1 = fmaf(wv.y, fq.x, h1); } \
    { const float2 wv = *reinterpret_cast<const float2*>((WPTR) + ((c4 * 4 + 1) * 64 + lane) * 2); \
      h0 = fmaf(wv.x, fq.y, h0); h1 = fmaf(wv.y, fq.y, h1); } \
    { const float2 wv = *reinterpret_cast<const float2*>((WPTR) + ((c4 * 4 + 2) * 64 + lane) * 2); \
      h0 = fmaf(wv.x, fq.z, h0); h1 = fmaf(wv.y, fq.z, h1); } \
    { const float2 wv = *reinterpret_cast<const float2*>((WPTR) + ((c4 * 4 + 3) * 64 + lane) * 2); \
      h0 = fmaf(wv.x, fq.w, h0); h1 = fmaf(wv.y, fq.w, h1); } \
  }

// ---------------------------------------------------------------------------
// Main kernel: 512-thread blocks = 8 waves, each wave owns one (b,p) tile.
// o2/j16 scheme: lane owns o in {lane, lane+64}, all 16 j in-lane
// (acc0/acc1[16] = 32 VGPRs). Weight = 1 coalesced dwordx2/lane/c (no
// redundancy -> 4x less L1 traffic). X-row reads uniform b128 broadcasts.
// Maxpool and FC entirely in-lane (no shuffles). Barriers phase-align the
// 8 waves so they stream the same weight lines together.
// ---------------------------------------------------------------------------
__global__ __launch_bounds__(512) void main_kernel(
    const float* __restrict__ xyz, const int* __restrict__ inds,
    const float* __restrict__ G,
    const float* __restrict__ w0x, const float* __restrict__ s0v, const float* __restrict__ t0v,
    const float* __restrict__ wl1, const float* __restrict__ s1v, const float* __restrict__ t1v,
    const float* __restrict__ wl2, const float* __restrict__ s2v, const float* __restrict__ t2v,
    const float* __restrict__ fl1, const float* __restrict__ fs1, const float* __restrict__ ft1,
    const float* __restrict__ fl2, const float* __restrict__ fs2, const float* __restrict__ ft2,
    const float* __restrict__ fl3, const float* __restrict__ b3, float* __restrict__ out)
{
  __shared__ __align__(16) float xt[8][NH * RP];   // 64 KB (8 waves)
  __shared__ float gxs[8][NS][3];
  __shared__ int   idxs[8][NS];

  const int w    = threadIdx.x >> 6;              // 0..7
  const int lane = threadIdx.x & 63;
  const int bid  = blockIdx.x * 8 + w;            // == b*NP + p
  const int b = bid >> 8;
  const int p = bid & 255;

  const float* xb = xyz + b * NPTS * 3;
  float* xs = &xt[w][0];

  // ---- ball query (bit-identical to reference), one wave per tile ----
  {
    const int ci = inds[bid];
    const float cx = xb[ci * 3 + 0], cy = xb[ci * 3 + 1], cz = xb[ci * 3 + 2];
    float nq;
    {
#pragma clang fp contract(off)
      nq = (cx * cx + cy * cy) + cz * cz;
    }
    const float R2 = 0.09f;
    unsigned mask = 0;
    int cnt = 0, firstn = NPTS;
    for (int j = 0; j < 16; ++j) {
#pragma clang fp contract(off)
      int n = lane * 16 + j;   // lane-major: global order == lexicographic
      float x = xb[n * 3 + 0], y = xb[n * 3 + 1], z = xb[n * 3 + 2];
      float nx = (x * x + y * y) + z * z;
      float dt = (cx * x + cy * y) + cz * z;
      float d2 = (nq + nx) - 2.0f * dt;
      if (d2 < R2) { mask |= 1u << j; ++cnt; if (firstn == NPTS) firstn = n; }
    }
    int inc = cnt;
    for (int off = 1; off < 64; off <<= 1) {
      int v = __shfl_up(inc, off);
      if (lane >= off) inc += v;
    }
    int rank  = inc - cnt;
    int total = __shfl(inc, 63);
    for (int j = 0; j < 16; ++j) {
      if (mask & (1u << j)) {
        if (rank < NS) {
          int n = lane * 16 + j;
          idxs[w][rank] = n;
          float x = xb[n * 3 + 0], y = xb[n * 3 + 1], z = xb[n * 3 + 2];
          gxs[w][rank][0] = (x - cx) / 0.3f;
          gxs[w][rank][1] = (y - cy) / 0.3f;
          gxs[w][rank][2] = (z - cz) / 0.3f;
        }
        ++rank;
      }
    }
    int fmin = firstn;
    for (int off2 = 32; off2 > 0; off2 >>= 1) {
      int ov = __shfl_xor(fmin, off2);
      fmin = min(fmin, ov);
    }
    if (lane < NS && lane >= total) {
      idxs[w][lane] = fmin;
      float x = xb[fmin * 3 + 0], y = xb[fmin * 3 + 1], z = xb[fmin * 3 + 2];
      gxs[w][lane][0] = (x - cx) / 0.3f;
      gxs[w][lane][1] = (y - cy) / 0.3f;
      gxs[w][lane][2] = (z - cz) / 0.3f;
    }
  }

  // ---- L0: lane computes x1 rows (lane) and (lane+64) ----
  {
    const float wa0 = w0x[lane],      wb0 = w0x[128 + lane],      wc0 = w0x[256 + lane];
    const float wa1 = w0x[lane + 64], wb1 = w0x[128 + lane + 64], wc1 = w0x[256 + lane + 64];
    const float ss0 = s0v[lane], tt0 = t0v[lane];
    const float ss1 = s0v[lane + 64], tt1 = t0v[lane + 64];
    float r0[16], r1[16];
#pragma unroll
    for (int j = 0; j < 16; ++j) {
      int nj = idxs[w][j];
      float gx = gxs[w][j][0], gy = gxs[w][j][1], gz = gxs[w][j][2];
      const float* gp = G + (b * NPTS + nj) * NH;
      float g0 = gp[lane], g1 = gp[lane + 64];
      float y0 = fmaf(wa0, gx, fmaf(wb0, gy, fmaf(wc0, gz, g0)));
      float y1 = fmaf(wa1, gx, fmaf(wb1, gy, fmaf(wc1, gz, g1)));
      r0[j] = fmaxf(fmaf(y0, ss0, tt0), 0.0f);
      r1[j] = fmaxf(fmaf(y1, ss1, tt1), 0.0f);
    }
    float* rowA = xs + lane * RP;
    float* rowB = xs + (lane + 64) * RP;
#pragma unroll
    for (int q = 0; q < 4; ++q) {
      reinterpret_cast<float4*>(rowA)[q] =
          make_float4(r0[4 * q], r0[4 * q + 1], r0[4 * q + 2], r0[4 * q + 3]);
      reinterpret_cast<float4*>(rowB)[q] =
          make_float4(r1[4 * q], r1[4 * q + 1], r1[4 * q + 2], r1[4 * q + 3]);
    }
  }
  __syncthreads();   // phase-align the 8 waves entering the L1 weight stream

  float acc0[16], acc1[16];
  float h0, h1;

  // ---- L1 ----
  MLP_LAYER(wl1)
  {
    const float ssa = s1v[lane], tta = t1v[lane];
    const float ssb = s1v[lane + 64], ttb = t1v[lane + 64];
    float r0[16], r1[16];
#pragma unroll
    for (int j = 0; j < 16; ++j) {
      r0[j] = fmaxf(fmaf(acc0[j], ssa, tta), 0.0f);
      r1[j] = fmaxf(fmaf(acc1[j], ssb, ttb), 0.0f);
    }
    float* rowA = xs + lane * RP;
    float* rowB = xs + (lane + 64) * RP;
#pragma unroll
    for (int q = 0; q < 4; ++q) {
      reinterpret_cast<float4*>(rowA)[q] =
          make_float4(r0[4 * q], r0[4 * q + 1], r0[4 * q + 2], r0[4 * q + 3]);
      reinterpret_cast<float4*>(rowB)[q] =
          make_float4(r1[4 * q], r1[4 * q + 1], r1[4 * q + 2], r1[4 * q + 3]);
    }
  }
  __syncthreads();   // phase-align entering the L2 weight stream

  // ---- L2 + in-lane maxpool ----
  MLP_LAYER(wl2)
  {
    const float ssa = s2v[lane], tta = t2v[lane];
    const float ssb = s2v[lane + 64], ttb = t2v[lane + 64];
    float fo0 = 0.0f, fo1 = 0.0f;
#pragma unroll
    for (int j = 0; j < 16; ++j) {
      fo0 = fmaxf(fo0, fmaxf(fmaf(acc0[j], ssa, tta), 0.0f));
      fo1 = fmaxf(fo1, fmaxf(fmaf(acc1[j], ssb, ttb), 0.0f));
    }
    xs[lane] = fo0;          // f vector -> xs[0..127] (X rows 0..7 are dead)
    xs[lane + 64] = fo1;
  }
  __syncthreads();   // phase-align entering the FC weight streams

  // ---- FC1: h -> xs[128..255] ----
  FC_LAYER(fl1, 0)
  xs[128 + lane]      = fmaxf(fmaf(h0, fs1[lane],      ft1[lane]),      0.0f);
  xs[128 + lane + 64] = fmaxf(fmaf(h1, fs1[lane + 64], ft1[lane + 64]), 0.0f);

  // ---- FC2: f2 -> xs[0..127] (reads [128..255], disjoint, in-wave order) --
  FC_LAYER(fl2, 128)
  xs[lane]      = fmaxf(fmaf(h0, fs2[lane],      ft2[lane]),      0.0f);
  xs[lane + 64] = fmaxf(fmaf(h1, fs2[lane + 64], ft2[lane + 64]), 0.0f);

  // ---- FC3 ----
  FC_LAYER(fl3, 0)
  out[(b * NOUT + lane) * NP + p] = h0 + b3[lane];            // lane < 97 always
  if (lane < NOUT - 64)
    out[(b * NOUT + lane + 64) * NP + p] = h1 + b3[lane + 64];
}

extern "C" void kernel_launch(void* const* d_in, const int* in_sizes, int n_in,
                              void* d_out, int out_size, void* d_ws, size_t ws_size,
                              hipStream_t stream) {
  const float* xyz      = (const float*)d_in[0];
  const float* features = (const float*)d_in[1];
  const float* sa_w0 = (const float*)d_in[2];
  const float* sa_s0 = (const float*)d_in[3];
  const float* sa_t0 = (const float*)d_in[4];
  const float* sa_w1 = (const float*)d_in[5];
  const float* sa_s1 = (const float*)d_in[6];
  const float* sa_t1 = (const float*)d_in[7];
  const float* sa_w2 = (const float*)d_in[8];
  const float* sa_s2 = (const float*)d_in[9];
  const float* sa_t2 = (const float*)d_in[10];
  const float* fc_w1 = (const float*)d_in[11];
  const float* fc_s1 = (const float*)d_in[12];
  const float* fc_t1 = (const float*)d_in[13];
  const float* fc_w2 = (const float*)d_in[14];
  const float* fc_s2 = (const float*)d_in[15];
  const float* fc_t2 = (const float*)d_in[16];
  const float* fc_w3 = (const float*)d_in[17];
  const float* fc_b3 = (const float*)d_in[18];
  float* out = (float*)d_out;

  char* ws = (char*)d_ws;
  int* inds = (int*)ws;            ws += (size_t)NB * NP * sizeof(int);
  float* w0l  = (float*)ws;        ws += (size_t)256 * 128 * sizeof(float);
  float* w0x  = (float*)ws;        ws += (size_t)3 * 128 * sizeof(float);
  float* wl1  = (float*)ws;        ws += (size_t)128 * 128 * sizeof(float);
  float* wl2  = (float*)ws;        ws += (size_t)128 * 128 * sizeof(float);
  float* fl1  = (float*)ws;        ws += (size_t)128 * 128 * sizeof(float);
  float* fl2  = (float*)ws;        ws += (size_t)128 * 128 * sizeof(float);
  float* fl3  = (float*)ws;        ws += (size_t)128 * 128 * sizeof(float);
  float* G    = (float*)ws;        ws += (size_t)NB * NPTS * NH * sizeof(float);

  prep_kernel<<<128, 256, 0, stream>>>(sa_w0, sa_w1, sa_w2, fc_w1, fc_w2, fc_w3,
                                       w0l, w0x, wl1, wl2, fl1, fl2, fl3);
  fused_fps_gfeat_kernel<<<NB + NB * (NPTS / 16), 64, 0, stream>>>(
      xyz, inds, features, w0l, G);
  main_kernel<<<NB * NP / 8, 512, 0, stream>>>(
      xyz, inds, G,
      w0x, sa_s0, sa_t0,
      wl1, sa_s1, sa_t1,
      wl2, sa_s2, sa_t2,
      fl1, fc_s1, fc_t1,
      fl2, fc_s2, fc_t2,
      fl3, fc_b3, out);
}

// Round 14
// 323.623 us; speedup vs baseline: 1.1752x; 1.1752x over previous
//
#include <hip/hip_runtime.h>

#define NB 32
#define NPTS 1024
#define NP 256
#define NS 16
#define NC 256
#define NH 128
#define NOUT 97
#define RP 16   // LDS row stride (floats)

// ---------------------------------------------------------------------------
// Prep. Two lane-split weight layouts:
//   w0l[(c*32+og)*4+k]  = sa_w0[og+32k][3+c]   (gfeat: 32 o-groups x 4)
//   wl*[(c*16+og)*8+k]  = W[og+16k][c]         (main:  16 o-groups x 8)
// ---------------------------------------------------------------------------
__global__ __launch_bounds__(256) void prep_kernel(
    const float* __restrict__ sa_w0, const float* __restrict__ sa_w1,
    const float* __restrict__ sa_w2, const float* __restrict__ fc_w1,
    const float* __restrict__ fc_w2, const float* __restrict__ fc_w3,
    float* __restrict__ w0l, float* __restrict__ w0x,
    float* __restrict__ wl1, float* __restrict__ wl2,
    float* __restrict__ fl1, float* __restrict__ fl2,
    float* __restrict__ fl3)
{
  int t = blockIdx.x * 256 + threadIdx.x;
  if (t >= 256 * 128) return;
  int c = t >> 7, o = t & 127;
  w0l[(c * 32 + (o & 31)) * 4 + (o >> 5)] = sa_w0[o * 259 + 3 + c];
  if (c < 3) w0x[c * 128 + o] = sa_w0[o * 259 + c];
  if (c < 128) {
    int qi = (c * 16 + (o & 15)) * 8 + (o >> 4);
    wl1[qi] = sa_w1[o * 128 + c];
    wl2[qi] = sa_w2[o * 128 + c];
    fl1[qi] = fc_w1[o * 128 + c];
    fl2[qi] = fc_w2[o * 128 + c];
    fl3[qi] = (o < NOUT) ? fc_w3[o * 128 + c] : 0.0f;
  }
}

// DPP reduction ladder steps (16-lane rows): row_shr:1/2/4/8, bcast15, bcast31
template <int CTRL>
__device__ __forceinline__ float dpp_fmax(float v) {
  float o = __int_as_float(
      __builtin_amdgcn_mov_dpp(__float_as_int(v), CTRL, 0xF, 0xF, true));
  return fmaxf(v, o);   // bound_ctrl: invalid lanes -> 0; v >= 0 so identity
}
template <int CTRL>
__device__ __forceinline__ unsigned dpp_umax(unsigned v) {
  unsigned o = (unsigned)__builtin_amdgcn_mov_dpp((int)v, CTRL, 0xF, 0xF, true);
  return v > o ? v : o;
}

// ---------------------------------------------------------------------------
// Fused FPS + gfeat, 64-thread (1-wave) blocks. (Round-9 measured version:
// no setprio — priority boost starved co-resident gfeat waves.)
//   blocks [0, NB):       FPS. All coords + dist in regs; LDS only for the
//                         uniform centroid lookup. Argmax = pure-VALU DPP
//                         ladder; local argmax fused into the dist update.
//   blocks [NB, NB+2048): gfeat, j-split-2: acc[4][8], full-c per lane.
// ---------------------------------------------------------------------------
__global__ __launch_bounds__(64) void fused_fps_gfeat_kernel(
    const float* __restrict__ xyz, int* __restrict__ inds,
    const float* __restrict__ features, const float* __restrict__ w0l,
    float* __restrict__ G)
{
  __shared__ __align__(16) float smem[NC * RP];   // 16 KB
  const int lane = threadIdx.x;

  if (blockIdx.x < NB) {
    // ------------------------- FPS -------------------------
    const int b = blockIdx.x;
    const float* xb = xyz + b * NPTS * 3;
    float* s_x = smem;
    float* s_y = smem + NPTS;
    float* s_z = smem + 2 * NPTS;
    float px[16], py[16], pz[16], dist[16];
    const float4* src = reinterpret_cast<const float4*>(xb + lane * 48);
#pragma unroll
    for (int q = 0; q < 4; ++q) {
      float4 v0 = src[3 * q], v1 = src[3 * q + 1], v2 = src[3 * q + 2];
      const float xv[4] = {v0.x, v0.w, v1.z, v2.y};
      const float yv[4] = {v0.y, v1.x, v1.w, v2.z};
      const float zv[4] = {v0.z, v1.y, v2.x, v2.w};
#pragma unroll
      for (int t = 0; t < 4; ++t) {
        int j = 4 * q + t;
        px[j] = xv[t]; py[j] = yv[t]; pz[j] = zv[t];
        s_x[lane * 16 + j] = xv[t];
        s_y[lane * 16 + j] = yv[t];
        s_z[lane * 16 + j] = zv[t];
      }
    }
#pragma unroll
    for (int j = 0; j < 16; ++j) dist[j] = 1e10f;
    int far = 0;
    for (int i = 0; i < NP; ++i) {
      if (lane == 0) inds[b * NP + i] = far;
      float cx = s_x[far], cy = s_y[far], cz = s_z[far];   // uniform broadcast
      float bv = -1.0f; int bi = 0;
#pragma unroll
      for (int j = 0; j < 16; ++j) {
#pragma clang fp contract(off)
        float dx = px[j] - cx;
        float dy = py[j] - cy;
        float dz = pz[j] - cz;
        float d = (dx * dx + dy * dy) + dz * dz;
        float nd = fminf(dist[j], d);
        dist[j] = nd;
        if (nd > bv) { bv = nd; bi = lane * 16 + j; }   // ascending j: first max
      }
      // global max of bv (pure VALU DPP ladder), lane 63 holds result
      float r = bv;
      r = dpp_fmax<0x111>(r);   // row_shr:1
      r = dpp_fmax<0x112>(r);   // row_shr:2
      r = dpp_fmax<0x114>(r);   // row_shr:4
      r = dpp_fmax<0x118>(r);   // row_shr:8
      r = dpp_fmax<0x142>(r);   // row_bcast:15
      r = dpp_fmax<0x143>(r);   // row_bcast:31
      float gmax = __int_as_float(__builtin_amdgcn_readlane(__float_as_int(r), 63));
      // first (min-index) lane value achieving gmax: max of ~idx among cands
      unsigned cand = (bv == gmax) ? ~(unsigned)bi : 0u;
      cand = dpp_umax<0x111>(cand);
      cand = dpp_umax<0x112>(cand);
      cand = dpp_umax<0x114>(cand);
      cand = dpp_umax<0x118>(cand);
      cand = dpp_umax<0x142>(cand);
      cand = dpp_umax<0x143>(cand);
      unsigned cmax = (unsigned)__builtin_amdgcn_readlane((int)cand, 63);
      far = (int)(~cmax);
    }
    return;
  }

  // ------------------------- gfeat (j-split-2) -------------------------
  const int blk = blockIdx.x - NB;
  const int b  = blk >> 6;
  const int n0 = (blk & 63) * 16;
  const int og = lane & 31;
  const int jg = lane >> 5;
  const int joff = jg * 8;
  const float* fb = features + b * NC * NPTS;
#pragma unroll
  for (int r = 0; r < 4; ++r) {
    int c = r * 64 + lane;
    const float4* s4 = reinterpret_cast<const float4*>(fb + c * NPTS + n0);
    float4 v0 = s4[0], v1 = s4[1], v2 = s4[2], v3 = s4[3];
    float* row = smem + c * RP;
    reinterpret_cast<float4*>(row)[0] = v0;
    reinterpret_cast<float4*>(row)[1] = v1;
    reinterpret_cast<float4*>(row)[2] = v2;
    reinterpret_cast<float4*>(row)[3] = v3;
  }
  // single wave: LDS write->read ordered in-wave by lgkmcnt.
  float acc[4][8];
#pragma unroll
  for (int k = 0; k < 4; ++k)
#pragma unroll
    for (int nn = 0; nn < 8; ++nn) acc[k][nn] = 0.0f;
#pragma unroll 2
  for (int c = 0; c < NC; ++c) {
    const float4 wq = *reinterpret_cast<const float4*>(w0l + (c * 32 + og) * 4);
    const float* row = smem + c * RP + joff;
    const float4 xa = reinterpret_cast<const float4*>(row)[0];
    const float4 xb4 = reinterpret_cast<const float4*>(row)[1];
    const float wk[4] = {wq.x, wq.y, wq.z, wq.w};
    const float xr[8] = {xa.x, xa.y, xa.z, xa.w, xb4.x, xb4.y, xb4.z, xb4.w};
#pragma unroll
    for (int k = 0; k < 4; ++k)
#pragma unroll
      for (int nn = 0; nn < 8; ++nn)
        acc[k][nn] = fmaf(wk[k], xr[nn], acc[k][nn]);
  }
#pragma unroll
  for (int k = 0; k < 4; ++k) {
    int o = og + 32 * k;
    float* gp = G + ((size_t)(b * NPTS + n0 + joff)) * NH + o;
#pragma unroll
    for (int nn = 0; nn < 8; ++nn) gp[nn * NH] = acc[k][nn];
  }
}

// ---------------------------------------------------------------------------
// Main kernel (Round-10 measured version, 218 us): 512-thread blocks = 8
// waves, each wave owns one (b,p) tile. __syncthreads() between phases keeps
// the 8 waves PHASE-ALIGNED so they stream the same weight lines together.
// j-split-4 per wave: lane=(og=lane&15, jg=lane>>4); acc[8][4]; one
// ds_read_b128 per c. Maxpool/FC merge via shfl_xor(16)+shfl_xor(32).
// ---------------------------------------------------------------------------
__global__ __launch_bounds__(512) void main_kernel(
    const float* __restrict__ xyz, const int* __restrict__ inds,
    const float* __restrict__ G,
    const float* __restrict__ w0x, const float* __restrict__ s0v, const float* __restrict__ t0v,
    const float* __restrict__ wl1, const float* __restrict__ s1v, const float* __restrict__ t1v,
    const float* __restrict__ wl2, const float* __restrict__ s2v, const float* __restrict__ t2v,
    const float* __restrict__ fl1, const float* __restrict__ fs1, const float* __restrict__ ft1,
    const float* __restrict__ fl2, const float* __restrict__ fs2, const float* __restrict__ ft2,
    const float* __restrict__ fl3, const float* __restrict__ b3, float* __restrict__ out)
{
  __shared__ __align__(16) float xt[8][NH * RP];   // 64 KB (8 waves)
  __shared__ float gxs[8][NS][3];
  __shared__ int   idxs[8][NS];

  const int w    = threadIdx.x >> 6;              // 0..7
  const int lane = threadIdx.x & 63;
  const int bid  = blockIdx.x * 8 + w;            // == b*NP + p
  const int b = bid >> 8;
  const int p = bid & 255;
  const int og = lane & 15;
  const int jg = lane >> 4;                        // 0..3
  const int joff = jg * 4;

  const float* xb = xyz + b * NPTS * 3;
  float* xs = &xt[w][0];

  // ---- ball query (bit-identical to reference), one wave per tile ----
  {
    const int ci = inds[bid];
    const float cx = xb[ci * 3 + 0], cy = xb[ci * 3 + 1], cz = xb[ci * 3 + 2];
    float nq;
    {
#pragma clang fp contract(off)
      nq = (cx * cx + cy * cy) + cz * cz;
    }
    const float R2 = 0.09f;
    unsigned mask = 0;
    int cnt = 0, firstn = NPTS;
    for (int j = 0; j < 16; ++j) {
#pragma clang fp contract(off)
      int n = lane * 16 + j;   // lane-major: global order == lexicographic
      float x = xb[n * 3 + 0], y = xb[n * 3 + 1], z = xb[n * 3 + 2];
      float nx = (x * x + y * y) + z * z;
      float dt = (cx * x + cy * y) + cz * z;
      float d2 = (nq + nx) - 2.0f * dt;
      if (d2 < R2) { mask |= 1u << j; ++cnt; if (firstn == NPTS) firstn = n; }
    }
    int inc = cnt;
    for (int off = 1; off < 64; off <<= 1) {
      int v = __shfl_up(inc, off);
      if (lane >= off) inc += v;
    }
    int rank  = inc - cnt;
    int total = __shfl(inc, 63);
    for (int j = 0; j < 16; ++j) {
      if (mask & (1u << j)) {
        if (rank < NS) {
          int n = lane * 16 + j;
          idxs[w][rank] = n;
          float x = xb[n * 3 + 0], y = xb[n * 3 + 1], z = xb[n * 3 + 2];
          gxs[w][rank][0] = (x - cx) / 0.3f;
          gxs[w][rank][1] = (y - cy) / 0.3f;
          gxs[w][rank][2] = (z - cz) / 0.3f;
        }
        ++rank;
      }
    }
    int fmin = firstn;
    for (int off2 = 32; off2 > 0; off2 >>= 1) {
      int ov = __shfl_xor(fmin, off2);
      fmin = min(fmin, ov);
    }
    if (lane < NS && lane >= total) {
      idxs[w][lane] = fmin;
      float x = xb[fmin * 3 + 0], y = xb[fmin * 3 + 1], z = xb[fmin * 3 + 2];
      gxs[w][lane][0] = (x - cx) / 0.3f;
      gxs[w][lane][1] = (y - cy) / 0.3f;
      gxs[w][lane][2] = (z - cz) / 0.3f;
    }
  }

  // ---- L0: lane computes x1 rows (lane) and (lane+64) ----
  {
    const float wa0 = w0x[lane],      wb0 = w0x[128 + lane],      wc0 = w0x[256 + lane];
    const float wa1 = w0x[lane + 64], wb1 = w0x[128 + lane + 64], wc1 = w0x[256 + lane + 64];
    const float ss0 = s0v[lane], tt0 = t0v[lane];
    const float ss1 = s0v[lane + 64], tt1 = t0v[lane + 64];
    float r0[16], r1[16];
#pragma unroll
    for (int j = 0; j < 16; ++j) {
      int nj = idxs[w][j];
      float gx = gxs[w][j][0], gy = gxs[w][j][1], gz = gxs[w][j][2];
      const float* gp = G + (b * NPTS + nj) * NH;
      float g0 = gp[lane], g1 = gp[lane + 64];
      float y0 = fmaf(wa0, gx, fmaf(wb0, gy, fmaf(wc0, gz, g0)));
      float y1 = fmaf(wa1, gx, fmaf(wb1, gy, fmaf(wc1, gz, g1)));
      r0[j] = fmaxf(fmaf(y0, ss0, tt0), 0.0f);
      r1[j] = fmaxf(fmaf(y1, ss1, tt1), 0.0f);
    }
    float* rowA = xs + lane * RP;
    float* rowB = xs + (lane + 64) * RP;
#pragma unroll
    for (int q = 0; q < 4; ++q) {
      reinterpret_cast<float4*>(rowA)[q] =
          make_float4(r0[4 * q], r0[4 * q + 1], r0[4 * q + 2], r0[4 * q + 3]);
      reinterpret_cast<float4*>(rowB)[q] =
          make_float4(r1[4 * q], r1[4 * q + 1], r1[4 * q + 2], r1[4 * q + 3]);
    }
  }
  __syncthreads();   // phase-align the 8 waves entering the L1 weight stream

  float acc[8][4];

  // ---- L1: lane computes o = og+16k (k 0..7), j in [joff, joff+4) ----
#pragma unroll
  for (int k = 0; k < 8; ++k)
#pragma unroll
    for (int nn = 0; nn < 4; ++nn) acc[k][nn] = 0.0f;
#pragma unroll 2
  for (int c = 0; c < NH; ++c) {
    const float* wp = wl1 + (c * 16 + og) * 8;
    const float4 wqa = reinterpret_cast<const float4*>(wp)[0];
    const float4 wqb = reinterpret_cast<const float4*>(wp)[1];
    const float4 xv = *reinterpret_cast<const float4*>(xs + c * RP + joff);
    const float wk[8] = {wqa.x, wqa.y, wqa.z, wqa.w, wqb.x, wqb.y, wqb.z, wqb.w};
    const float xr[4] = {xv.x, xv.y, xv.z, xv.w};
#pragma unroll
    for (int k = 0; k < 8; ++k)
#pragma unroll
      for (int nn = 0; nn < 4; ++nn)
        acc[k][nn] = fmaf(wk[k], xr[nn], acc[k][nn]);
  }
  // BN+ReLU, write x2 chunks (all x1 reads complete in-wave before writes)
#pragma unroll
  for (int k = 0; k < 8; ++k) {
    int o = og + 16 * k;
    const float ss = s1v[o], tt = t1v[o];
    float4 r;
    r.x = fmaxf(fmaf(acc[k][0], ss, tt), 0.0f);
    r.y = fmaxf(fmaf(acc[k][1], ss, tt), 0.0f);
    r.z = fmaxf(fmaf(acc[k][2], ss, tt), 0.0f);
    r.w = fmaxf(fmaf(acc[k][3], ss, tt), 0.0f);
    *reinterpret_cast<float4*>(xs + o * RP + joff) = r;
  }
  __syncthreads();   // phase-align entering the L2 weight stream

  // ---- L2 + maxpool ----
#pragma unroll
  for (int k = 0; k < 8; ++k)
#pragma unroll
    for (int nn = 0; nn < 4; ++nn) acc[k][nn] = 0.0f;
#pragma unroll 2
  for (int c = 0; c < NH; ++c) {
    const float* wp = wl2 + (c * 16 + og) * 8;
    const float4 wqa = reinterpret_cast<const float4*>(wp)[0];
    const float4 wqb = reinterpret_cast<const float4*>(wp)[1];
    const float4 xv = *reinterpret_cast<const float4*>(xs + c * RP + joff);
    const float wk[8] = {wqa.x, wqa.y, wqa.z, wqa.w, wqb.x, wqb.y, wqb.z, wqb.w};
    const float xr[4] = {xv.x, xv.y, xv.z, xv.w};
#pragma unroll
    for (int k = 0; k < 8; ++k)
#pragma unroll
      for (int nn = 0; nn < 4; ++nn)
        acc[k][nn] = fmaf(wk[k], xr[nn], acc[k][nn]);
  }
  // BN+ReLU+max over local 4 j's, then cross-jg; f -> xs[0..127]
#pragma unroll
  for (int k = 0; k < 8; ++k) {
    int o = og + 16 * k;
    const float ss = s2v[o], tt = t2v[o];
    float fo = 0.0f;
#pragma unroll
    for (int nn = 0; nn < 4; ++nn)
      fo = fmaxf(fo, fmaxf(fmaf(acc[k][nn], ss, tt), 0.0f));
    fo = fmaxf(fo, __shfl_xor(fo, 16));
    fo = fmaxf(fo, __shfl_xor(fo, 32));
    if (jg == 0) xs[o] = fo;
  }
  __syncthreads();   // phase-align entering the FC weight streams

  const int cb = jg * 32;   // c-split-4 for FC stages

  // ---- FC1: h -> xs[128..255] ----
  {
    float h[8] = {0, 0, 0, 0, 0, 0, 0, 0};
#pragma unroll 4
    for (int cl = 0; cl < 32; ++cl) {
      int c = cb + cl;
      const float fv = xs[c];
      const float* wp = fl1 + (c * 16 + og) * 8;
      const float4 wqa = reinterpret_cast<const float4*>(wp)[0];
      const float4 wqb = reinterpret_cast<const float4*>(wp)[1];
      h[0] = fmaf(wqa.x, fv, h[0]); h[1] = fmaf(wqa.y, fv, h[1]);
      h[2] = fmaf(wqa.z, fv, h[2]); h[3] = fmaf(wqa.w, fv, h[3]);
      h[4] = fmaf(wqb.x, fv, h[4]); h[5] = fmaf(wqb.y, fv, h[5]);
      h[6] = fmaf(wqb.z, fv, h[6]); h[7] = fmaf(wqb.w, fv, h[7]);
    }
#pragma unroll
    for (int k = 0; k < 8; ++k) {
      h[k] += __shfl_xor(h[k], 16);
      h[k] += __shfl_xor(h[k], 32);
      int o = og + 16 * k;
      if (jg == 0) xs[128 + o] = fmaxf(fmaf(h[k], fs1[o], ft1[o]), 0.0f);
    }
  }

  // ---- FC2: f2 -> xs[0..127] ----
  {
    float h[8] = {0, 0, 0, 0, 0, 0, 0, 0};
#pragma unroll 4
    for (int cl = 0; cl < 32; ++cl) {
      int c = cb + cl;
      const float fv = xs[128 + c];
      const float* wp = fl2 + (c * 16 + og) * 8;
      const float4 wqa = reinterpret_cast<const float4*>(wp)[0];
      const float4 wqb = reinterpret_cast<const float4*>(wp)[1];
      h[0] = fmaf(wqa.x, fv, h[0]); h[1] = fmaf(wqa.y, fv, h[1]);
      h[2] = fmaf(wqa.z, fv, h[2]); h[3] = fmaf(wqa.w, fv, h[3]);
      h[4] = fmaf(wqb.x, fv, h[4]); h[5] = fmaf(wqb.y, fv, h[5]);
      h[6] = fmaf(wqb.z, fv, h[6]); h[7] = fmaf(wqb.w, fv, h[7]);
    }
#pragma unroll
    for (int k = 0; k < 8; ++k) {
      h[k] += __shfl_xor(h[k], 16);
      h[k] += __shfl_xor(h[k], 32);
      int o = og + 16 * k;
      if (jg == 0) xs[o] = fmaxf(fmaf(h[k], fs2[o], ft2[o]), 0.0f);
    }
  }

  // ---- FC3 ----
  {
    float h[8] = {0, 0, 0, 0, 0, 0, 0, 0};
#pragma unroll 4
    for (int cl = 0; cl < 32; ++cl) {
      int c = cb + cl;
      const float fv = xs[c];
      const float* wp = fl3 + (c * 16 + og) * 8;
      const float4 wqa = reinterpret_cast<const float4*>(wp)[0];
      const float4 wqb = reinterpret_cast<const float4*>(wp)[1];
      h[0] = fmaf(wqa.x, fv, h[0]); h[1] = fmaf(wqa.y, fv, h[1]);
      h[2] = fmaf(wqa.z, fv, h[2]); h[3] = fmaf(wqa.w, fv, h[3]);
      h[4] = fmaf(wqb.x, fv, h[4]); h[5] = fmaf(wqb.y, fv, h[5]);
      h[6] = fmaf(wqb.z, fv, h[6]); h[7] = fmaf(wqb.w, fv, h[7]);
    }
#pragma unroll
    for (int k = 0; k < 8; ++k) {
      h[k] += __shfl_xor(h[k], 16);
      h[k] += __shfl_xor(h[k], 32);
      int o = og + 16 * k;
      if (jg == 0 && o < NOUT) out[(b * NOUT + o) * NP + p] = h[k] + b3[o];
    }
  }
}

extern "C" void kernel_launch(void* const* d_in, const int* in_sizes, int n_in,
                              void* d_out, int out_size, void* d_ws, size_t ws_size,
                              hipStream_t stream) {
  const float* xyz      = (const float*)d_in[0];
  const float* features = (const float*)d_in[1];
  const float* sa_w0 = (const float*)d_in[2];
  const float* sa_s0 = (const float*)d_in[3];
  const float* sa_t0 = (const float*)d_in[4];
  const float* sa_w1 = (const float*)d_in[5];
  const float* sa_s1 = (const float*)d_in[6];
  const float* sa_t1 = (const float*)d_in[7];
  const float* sa_w2 = (const float*)d_in[8];
  const float* sa_s2 = (const float*)d_in[9];
  const float* sa_t2 = (const float*)d_in[10];
  const float* fc_w1 = (const float*)d_in[11];
  const float* fc_s1 = (const float*)d_in[12];
  const float* fc_t1 = (const float*)d_in[13];
  const float* fc_w2 = (const float*)d_in[14];
  const float* fc_s2 = (const float*)d_in[15];
  const float* fc_t2 = (const float*)d_in[16];
  const float* fc_w3 = (const float*)d_in[17];
  const float* fc_b3 = (const float*)d_in[18];
  float* out = (float*)d_out;

  char* ws = (char*)d_ws;
  int* inds = (int*)ws;            ws += (size_t)NB * NP * sizeof(int);
  float* w0l  = (float*)ws;        ws += (size_t)256 * 128 * sizeof(float);
  float* w0x  = (float*)ws;        ws += (size_t)3 * 128 * sizeof(float);
  float* wl1  = (float*)ws;        ws += (size_t)128 * 128 * sizeof(float);
  float* wl2  = (float*)ws;        ws += (size_t)128 * 128 * sizeof(float);
  float* fl1  = (float*)ws;        ws += (size_t)128 * 128 * sizeof(float);
  float* fl2  = (float*)ws;        ws += (size_t)128 * 128 * sizeof(float);
  float* fl3  = (float*)ws;        ws += (size_t)128 * 128 * sizeof(float);
  float* G    = (float*)ws;        ws += (size_t)NB * NPTS * NH * sizeof(float);

  prep_kernel<<<128, 256, 0, stream>>>(sa_w0, sa_w1, sa_w2, fc_w1, fc_w2, fc_w3,
                                       w0l, w0x, wl1, wl2, fl1, fl2, fl3);
  fused_fps_gfeat_kernel<<<NB + NB * (NPTS / 16), 64, 0, stream>>>(
      xyz, inds, features, w0l, G);
  main_kernel<<<NB * NP / 8, 512, 0, stream>>>(
      xyz, inds, G,
      w0x, sa_s0, sa_t0,
      wl1, sa_s1, sa_t1,
      wl2, sa_s2, sa_t2,
      fl1, fc_s1, fc_t1,
      fl2, fc_s2, fc_t2,
      fl3, fc_b3, out);
}

// Round 15
// 304.930 us; speedup vs baseline: 1.2473x; 1.0613x over previous
//
#include <hip/hip_runtime.h>

#define NB 32
#define NPTS 1024
#define NP 256
#define NS 16
#define NC 256
#define NH 128
#define NOUT 97
#define RP 16   // LDS row stride (floats)

// ---------------------------------------------------------------------------
// Prep.
//   w0l[(c*32+og)*4+k] = sa_w0[og+32k][3+c]   (gfeat: 32 o-groups x 4)
//   o2 layout for all main-kernel matrices: wl[(c*64+m)*2+t] = W[m+64t][c]
//   (one coalesced dwordx2 per lane per c — zero intra-wave redundancy)
// ---------------------------------------------------------------------------
__global__ __launch_bounds__(256) void prep_kernel(
    const float* __restrict__ sa_w0, const float* __restrict__ sa_w1,
    const float* __restrict__ sa_w2, const float* __restrict__ fc_w1,
    const float* __restrict__ fc_w2, const float* __restrict__ fc_w3,
    float* __restrict__ w0l, float* __restrict__ w0x,
    float* __restrict__ wl1, float* __restrict__ wl2,
    float* __restrict__ fl1, float* __restrict__ fl2,
    float* __restrict__ fl3)
{
  int t = blockIdx.x * 256 + threadIdx.x;
  if (t >= 256 * 128) return;
  int c = t >> 7, o = t & 127;
  w0l[(c * 32 + (o & 31)) * 4 + (o >> 5)] = sa_w0[o * 259 + 3 + c];
  if (c < 3) w0x[c * 128 + o] = sa_w0[o * 259 + c];
  if (c < 128) {
    int qi = (c * 64 + (o & 63)) * 2 + (o >> 6);
    wl1[qi] = sa_w1[o * 128 + c];
    wl2[qi] = sa_w2[o * 128 + c];
    fl1[qi] = fc_w1[o * 128 + c];
    fl2[qi] = fc_w2[o * 128 + c];
    fl3[qi] = (o < NOUT) ? fc_w3[o * 128 + c] : 0.0f;
  }
}

// DPP reduction ladder steps (16-lane rows): row_shr:1/2/4/8, bcast15, bcast31
template <int CTRL>
__device__ __forceinline__ float dpp_fmax(float v) {
  float o = __int_as_float(
      __builtin_amdgcn_mov_dpp(__float_as_int(v), CTRL, 0xF, 0xF, true));
  return fmaxf(v, o);   // bound_ctrl: invalid lanes -> 0; v >= 0 so identity
}
template <int CTRL>
__device__ __forceinline__ unsigned dpp_umax(unsigned v) {
  unsigned o = (unsigned)__builtin_amdgcn_mov_dpp((int)v, CTRL, 0xF, 0xF, true);
  return v > o ? v : o;
}

// ---------------------------------------------------------------------------
// Fused FPS + gfeat (Round-14 measured version, unchanged).
// ---------------------------------------------------------------------------
__global__ __launch_bounds__(64) void fused_fps_gfeat_kernel(
    const float* __restrict__ xyz, int* __restrict__ inds,
    const float* __restrict__ features, const float* __restrict__ w0l,
    float* __restrict__ G)
{
  __shared__ __align__(16) float smem[NC * RP];   // 16 KB
  const int lane = threadIdx.x;

  if (blockIdx.x < NB) {
    // ------------------------- FPS -------------------------
    const int b = blockIdx.x;
    const float* xb = xyz + b * NPTS * 3;
    float* s_x = smem;
    float* s_y = smem + NPTS;
    float* s_z = smem + 2 * NPTS;
    float px[16], py[16], pz[16], dist[16];
    const float4* src = reinterpret_cast<const float4*>(xb + lane * 48);
#pragma unroll
    for (int q = 0; q < 4; ++q) {
      float4 v0 = src[3 * q], v1 = src[3 * q + 1], v2 = src[3 * q + 2];
      const float xv[4] = {v0.x, v0.w, v1.z, v2.y};
      const float yv[4] = {v0.y, v1.x, v1.w, v2.z};
      const float zv[4] = {v0.z, v1.y, v2.x, v2.w};
#pragma unroll
      for (int t = 0; t < 4; ++t) {
        int j = 4 * q + t;
        px[j] = xv[t]; py[j] = yv[t]; pz[j] = zv[t];
        s_x[lane * 16 + j] = xv[t];
        s_y[lane * 16 + j] = yv[t];
        s_z[lane * 16 + j] = zv[t];
      }
    }
#pragma unroll
    for (int j = 0; j < 16; ++j) dist[j] = 1e10f;
    int far = 0;
    for (int i = 0; i < NP; ++i) {
      if (lane == 0) inds[b * NP + i] = far;
      float cx = s_x[far], cy = s_y[far], cz = s_z[far];   // uniform broadcast
      float bv = -1.0f; int bi = 0;
#pragma unroll
      for (int j = 0; j < 16; ++j) {
#pragma clang fp contract(off)
        float dx = px[j] - cx;
        float dy = py[j] - cy;
        float dz = pz[j] - cz;
        float d = (dx * dx + dy * dy) + dz * dz;
        float nd = fminf(dist[j], d);
        dist[j] = nd;
        if (nd > bv) { bv = nd; bi = lane * 16 + j; }   // ascending j: first max
      }
      float r = bv;
      r = dpp_fmax<0x111>(r);
      r = dpp_fmax<0x112>(r);
      r = dpp_fmax<0x114>(r);
      r = dpp_fmax<0x118>(r);
      r = dpp_fmax<0x142>(r);
      r = dpp_fmax<0x143>(r);
      float gmax = __int_as_float(__builtin_amdgcn_readlane(__float_as_int(r), 63));
      unsigned cand = (bv == gmax) ? ~(unsigned)bi : 0u;
      cand = dpp_umax<0x111>(cand);
      cand = dpp_umax<0x112>(cand);
      cand = dpp_umax<0x114>(cand);
      cand = dpp_umax<0x118>(cand);
      cand = dpp_umax<0x142>(cand);
      cand = dpp_umax<0x143>(cand);
      unsigned cmax = (unsigned)__builtin_amdgcn_readlane((int)cand, 63);
      far = (int)(~cmax);
    }
    return;
  }

  // ------------------------- gfeat (j-split-2) -------------------------
  const int blk = blockIdx.x - NB;
  const int b  = blk >> 6;
  const int n0 = (blk & 63) * 16;
  const int og = lane & 31;
  const int jg = lane >> 5;
  const int joff = jg * 8;
  const float* fb = features + b * NC * NPTS;
#pragma unroll
  for (int r = 0; r < 4; ++r) {
    int c = r * 64 + lane;
    const float4* s4 = reinterpret_cast<const float4*>(fb + c * NPTS + n0);
    float4 v0 = s4[0], v1 = s4[1], v2 = s4[2], v3 = s4[3];
    float* row = smem + c * RP;
    reinterpret_cast<float4*>(row)[0] = v0;
    reinterpret_cast<float4*>(row)[1] = v1;
    reinterpret_cast<float4*>(row)[2] = v2;
    reinterpret_cast<float4*>(row)[3] = v3;
  }
  float acc[4][8];
#pragma unroll
  for (int k = 0; k < 4; ++k)
#pragma unroll
    for (int nn = 0; nn < 8; ++nn) acc[k][nn] = 0.0f;
#pragma unroll 2
  for (int c = 0; c < NC; ++c) {
    const float4 wq = *reinterpret_cast<const float4*>(w0l + (c * 32 + og) * 4);
    const float* row = smem + c * RP + joff;
    const float4 xa = reinterpret_cast<const float4*>(row)[0];
    const float4 xb4 = reinterpret_cast<const float4*>(row)[1];
    const float wk[4] = {wq.x, wq.y, wq.z, wq.w};
    const float xr[8] = {xa.x, xa.y, xa.z, xa.w, xb4.x, xb4.y, xb4.z, xb4.w};
#pragma unroll
    for (int k = 0; k < 4; ++k)
#pragma unroll
      for (int nn = 0; nn < 8; ++nn)
        acc[k][nn] = fmaf(wk[k], xr[nn], acc[k][nn]);
  }
#pragma unroll
  for (int k = 0; k < 4; ++k) {
    int o = og + 32 * k;
    float* gp = G + ((size_t)(b * NPTS + n0 + joff)) * NH + o;
#pragma unroll
    for (int nn = 0; nn < 8; ++nn) gp[nn * NH] = acc[k][nn];
  }
}

// ---------------------------------------------------------------------------
// Templated L0->L1->L2->maxpool for J active neighbor slots (J = 4/8/16).
// o2 scheme: lane owns o in {lane, lane+64}; j in registers (acc0/acc1[J]).
// Slots >= total are duplicates of slot 0 (ball-query fill), so maxpool over
// J >= total slots equals maxpool over all 16.
// ---------------------------------------------------------------------------
template <int J>
__device__ __forceinline__ void mlp_tiles(
    float* __restrict__ xs, const int lane,
    const float* __restrict__ gbase,
    const int* __restrict__ idxw, const float* __restrict__ gxw,
    const float* __restrict__ w0x, const float* __restrict__ s0v, const float* __restrict__ t0v,
    const float* __restrict__ wl1, const float* __restrict__ s1v, const float* __restrict__ t1v,
    const float* __restrict__ wl2, const float* __restrict__ s2v, const float* __restrict__ t2v,
    float& fo0, float& fo1)
{
  // ---- L0: rows c=lane, c=lane+64, slots 0..J-1 ----
  {
    const float wa0 = w0x[lane],      wb0 = w0x[128 + lane],      wc0 = w0x[256 + lane];
    const float wa1 = w0x[64 + lane], wb1 = w0x[192 + lane],      wc1 = w0x[320 + lane];
    const float ss0 = s0v[lane], tt0 = t0v[lane];
    const float ss1 = s0v[64 + lane], tt1 = t0v[64 + lane];
    float r0[J], r1[J];
#pragma unroll
    for (int j = 0; j < J; ++j) {
      int nj = idxw[j];
      float gx = gxw[j * 3 + 0], gy = gxw[j * 3 + 1], gz = gxw[j * 3 + 2];
      const float* gp = gbase + nj * NH;
      float g0 = gp[lane], g1 = gp[lane + 64];
      float y0 = fmaf(wa0, gx, fmaf(wb0, gy, fmaf(wc0, gz, g0)));
      float y1 = fmaf(wa1, gx, fmaf(wb1, gy, fmaf(wc1, gz, g1)));
      r0[j] = fmaxf(fmaf(y0, ss0, tt0), 0.0f);
      r1[j] = fmaxf(fmaf(y1, ss1, tt1), 0.0f);
    }
#pragma unroll
    for (int q = 0; q < J / 4; ++q) {
      *reinterpret_cast<float4*>(xs + lane * RP + q * 4) =
          make_float4(r0[4 * q], r0[4 * q + 1], r0[4 * q + 2], r0[4 * q + 3]);
      *reinterpret_cast<float4*>(xs + (lane + 64) * RP + q * 4) =
          make_float4(r1[4 * q], r1[4 * q + 1], r1[4 * q + 2], r1[4 * q + 3]);
    }
  }

  float acc0[J], acc1[J];

  // ---- L1 ----
#pragma unroll
  for (int j = 0; j < J; ++j) { acc0[j] = 0.0f; acc1[j] = 0.0f; }
#pragma unroll 2
  for (int c = 0; c < NH; ++c) {
    const float2 wv = *reinterpret_cast<const float2*>(wl1 + (c * 64 + lane) * 2);
#pragma unroll
    for (int q = 0; q < J / 4; ++q) {
      const float4 xq = *reinterpret_cast<const float4*>(xs + c * RP + q * 4);
      acc0[4 * q + 0] = fmaf(wv.x, xq.x, acc0[4 * q + 0]);
      acc1[4 * q + 0] = fmaf(wv.y, xq.x, acc1[4 * q + 0]);
      acc0[4 * q + 1] = fmaf(wv.x, xq.y, acc0[4 * q + 1]);
      acc1[4 * q + 1] = fmaf(wv.y, xq.y, acc1[4 * q + 1]);
      acc0[4 * q + 2] = fmaf(wv.x, xq.z, acc0[4 * q + 2]);
      acc1[4 * q + 2] = fmaf(wv.y, xq.z, acc1[4 * q + 2]);
      acc0[4 * q + 3] = fmaf(wv.x, xq.w, acc0[4 * q + 3]);
      acc1[4 * q + 3] = fmaf(wv.y, xq.w, acc1[4 * q + 3]);
    }
  }
  // BN+ReLU, write x2 (in-wave LDS ordering: x1 reads precede these writes)
  {
    const float ssa = s1v[lane], tta = t1v[lane];
    const float ssb = s1v[64 + lane], ttb = t1v[64 + lane];
#pragma unroll
    for (int q = 0; q < J / 4; ++q) {
      float4 ra, rb;
      ra.x = fmaxf(fmaf(acc0[4 * q + 0], ssa, tta), 0.0f);
      ra.y = fmaxf(fmaf(acc0[4 * q + 1], ssa, tta), 0.0f);
      ra.z = fmaxf(fmaf(acc0[4 * q + 2], ssa, tta), 0.0f);
      ra.w = fmaxf(fmaf(acc0[4 * q + 3], ssa, tta), 0.0f);
      rb.x = fmaxf(fmaf(acc1[4 * q + 0], ssb, ttb), 0.0f);
      rb.y = fmaxf(fmaf(acc1[4 * q + 1], ssb, ttb), 0.0f);
      rb.z = fmaxf(fmaf(acc1[4 * q + 2], ssb, ttb), 0.0f);
      rb.w = fmaxf(fmaf(acc1[4 * q + 3], ssb, ttb), 0.0f);
      *reinterpret_cast<float4*>(xs + lane * RP + q * 4) = ra;
      *reinterpret_cast<float4*>(xs + (lane + 64) * RP + q * 4) = rb;
    }
  }

  // ---- L2 ----
#pragma unroll
  for (int j = 0; j < J; ++j) { acc0[j] = 0.0f; acc1[j] = 0.0f; }
#pragma unroll 2
  for (int c = 0; c < NH; ++c) {
    const float2 wv = *reinterpret_cast<const float2*>(wl2 + (c * 64 + lane) * 2);
#pragma unroll
    for (int q = 0; q < J / 4; ++q) {
      const float4 xq = *reinterpret_cast<const float4*>(xs + c * RP + q * 4);
      acc0[4 * q + 0] = fmaf(wv.x, xq.x, acc0[4 * q + 0]);
      acc1[4 * q + 0] = fmaf(wv.y, xq.x, acc1[4 * q + 0]);
      acc0[4 * q + 1] = fmaf(wv.x, xq.y, acc0[4 * q + 1]);
      acc1[4 * q + 1] = fmaf(wv.y, xq.y, acc1[4 * q + 1]);
      acc0[4 * q + 2] = fmaf(wv.x, xq.z, acc0[4 * q + 2]);
      acc1[4 * q + 2] = fmaf(wv.y, xq.z, acc1[4 * q + 2]);
      acc0[4 * q + 3] = fmaf(wv.x, xq.w, acc0[4 * q + 3]);
      acc1[4 * q + 3] = fmaf(wv.y, xq.w, acc1[4 * q + 3]);
    }
  }
  // ---- in-lane maxpool ----
  {
    const float ssa = s2v[lane], tta = t2v[lane];
    const float ssb = s2v[64 + lane], ttb = t2v[64 + lane];
    fo0 = 0.0f; fo1 = 0.0f;
#pragma unroll
    for (int j = 0; j < J; ++j) {
      fo0 = fmaxf(fo0, fmaxf(fmaf(acc0[j], ssa, tta), 0.0f));
      fo1 = fmaxf(fo1, fmaxf(fmaf(acc1[j], ssb, ttb), 0.0f));
    }
  }
}

// FC matvec: h0/h1 += W[lane][c]*f[c], W[lane+64][c]*f[c]; f read uniform.
#define FC_LAYER(WPTR, SRCOFF) \
  h0 = 0.0f; h1 = 0.0f; \
  _Pragma("unroll 4") \
  for (int c4 = 0; c4 < 32; ++c4) { \
    const float4 fq = *reinterpret_cast<const float4*>(xs + (SRCOFF) + c4 * 4); \
    { const float2 wv = *reinterpret_cast<const float2*>((WPTR) + ((c4 * 4 + 0) * 64 + lane) * 2); \
      h0 = fmaf(wv.x, fq.x, h0); h1 = fmaf(wv.y, fq.x, h1); } \
    { const float2 wv = *reinterpret_cast<const float2*>((WPTR) + ((c4 * 4 + 1) * 64 + lane) * 2); \
      h0 = fmaf(wv.x, fq.y, h0); h1 = fmaf(wv.y, fq.y, h1); } \
    { const float2 wv = *reinterpret_cast<const float2*>((WPTR) + ((c4 * 4 + 2) * 64 + lane) * 2); \
      h0 = fmaf(wv.x, fq.z, h0); h1 = fmaf(wv.y, fq.z, h1); } \
    { const float2 wv = *reinterpret_cast<const float2*>((WPTR) + ((c4 * 4 + 3) * 64 + lane) * 2); \
      h0 = fmaf(wv.x, fq.w, h0); h1 = fmaf(wv.y, fq.w, h1); } \
  }

// ---------------------------------------------------------------------------
// Main kernel: 512-thread blocks = 8 INDEPENDENT waves, each owns one (b,p)
// tile. No barriers (waves have private LDS planes; mixed-J waves must not
// lockstep). Wave-uniform dispatch on total -> J in {4,8,16}: slots >= total
// duplicate slot 0, so only J slots need computing.
// ---------------------------------------------------------------------------
__global__ __launch_bounds__(512) void main_kernel(
    const float* __restrict__ xyz, const int* __restrict__ inds,
    const float* __restrict__ G,
    const float* __restrict__ w0x, const float* __restrict__ s0v, const float* __restrict__ t0v,
    const float* __restrict__ wl1, const float* __restrict__ s1v, const float* __restrict__ t1v,
    const float* __restrict__ wl2, const float* __restrict__ s2v, const float* __restrict__ t2v,
    const float* __restrict__ fl1, const float* __restrict__ fs1, const float* __restrict__ ft1,
    const float* __restrict__ fl2, const float* __restrict__ fs2, const float* __restrict__ ft2,
    const float* __restrict__ fl3, const float* __restrict__ b3, float* __restrict__ out)
{
  __shared__ __align__(16) float xt[8][NH * RP];   // 64 KB (8 waves)
  __shared__ float gxs[8][NS][3];
  __shared__ int   idxs[8][NS];

  const int w    = threadIdx.x >> 6;              // 0..7
  const int lane = threadIdx.x & 63;
  const int bid  = blockIdx.x * 8 + w;            // == b*NP + p
  const int b = bid >> 8;
  const int p = bid & 255;

  const float* xb = xyz + b * NPTS * 3;
  float* xs = &xt[w][0];

  // ---- ball query (bit-identical to reference), one wave per tile ----
  int total;
  {
    const int ci = inds[bid];
    const float cx = xb[ci * 3 + 0], cy = xb[ci * 3 + 1], cz = xb[ci * 3 + 2];
    float nq;
    {
#pragma clang fp contract(off)
      nq = (cx * cx + cy * cy) + cz * cz;
    }
    const float R2 = 0.09f;
    unsigned mask = 0;
    int cnt = 0, firstn = NPTS;
    for (int j = 0; j < 16; ++j) {
#pragma clang fp contract(off)
      int n = lane * 16 + j;   // lane-major: global order == lexicographic
      float x = xb[n * 3 + 0], y = xb[n * 3 + 1], z = xb[n * 3 + 2];
      float nx = (x * x + y * y) + z * z;
      float dt = (cx * x + cy * y) + cz * z;
      float d2 = (nq + nx) - 2.0f * dt;
      if (d2 < R2) { mask |= 1u << j; ++cnt; if (firstn == NPTS) firstn = n; }
    }
    int inc = cnt;
    for (int off = 1; off < 64; off <<= 1) {
      int v = __shfl_up(inc, off);
      if (lane >= off) inc += v;
    }
    int rank = inc - cnt;
    total = __shfl(inc, 63);
    for (int j = 0; j < 16; ++j) {
      if (mask & (1u << j)) {
        if (rank < NS) {
          int n = lane * 16 + j;
          idxs[w][rank] = n;
          float x = xb[n * 3 + 0], y = xb[n * 3 + 1], z = xb[n * 3 + 2];
          gxs[w][rank][0] = (x - cx) / 0.3f;
          gxs[w][rank][1] = (y - cy) / 0.3f;
          gxs[w][rank][2] = (z - cz) / 0.3f;
        }
        ++rank;
      }
    }
    int fmin = firstn;
    for (int off2 = 32; off2 > 0; off2 >>= 1) {
      int ov = __shfl_xor(fmin, off2);
      fmin = min(fmin, ov);
    }
    if (lane < NS && lane >= total) {
      idxs[w][lane] = fmin;
      float x = xb[fmin * 3 + 0], y = xb[fmin * 3 + 1], z = xb[fmin * 3 + 2];
      gxs[w][lane][0] = (x - cx) / 0.3f;
      gxs[w][lane][1] = (y - cy) / 0.3f;
      gxs[w][lane][2] = (z - cz) / 0.3f;
    }
  }

  // ---- L0 -> L1 -> L2 -> maxpool, sized to the active slot count ----
  const float* gbase = G + (size_t)b * NPTS * NH;
  float fo0, fo1;
  if (total <= 4) {
    mlp_tiles<4>(xs, lane, gbase, idxs[w], &gxs[w][0][0],
                 w0x, s0v, t0v, wl1, s1v, t1v, wl2, s2v, t2v, fo0, fo1);
  } else if (total <= 8) {
    mlp_tiles<8>(xs, lane, gbase, idxs[w], &gxs[w][0][0],
                 w0x, s0v, t0v, wl1, s1v, t1v, wl2, s2v, t2v, fo0, fo1);
  } else {
    mlp_tiles<16>(xs, lane, gbase, idxs[w], &gxs[w][0][0],
                  w0x, s0v, t0v, wl1, s1v, t1v, wl2, s2v, t2v, fo0, fo1);
  }
  xs[lane] = fo0;          // f vector -> xs[0..127]
  xs[lane + 64] = fo1;

  float h0, h1;

  // ---- FC1: h -> xs[128..255] ----
  FC_LAYER(fl1, 0)
  xs[128 + lane]      = fmaxf(fmaf(h0, fs1[lane],      ft1[lane]),      0.0f);
  xs[128 + lane + 64] = fmaxf(fmaf(h1, fs1[lane + 64], ft1[lane + 64]), 0.0f);

  // ---- FC2: f2 -> xs[0..127] ----
  FC_LAYER(fl2, 128)
  xs[lane]      = fmaxf(fmaf(h0, fs2[lane],      ft2[lane]),      0.0f);
  xs[lane + 64] = fmaxf(fmaf(h1, fs2[lane + 64], ft2[lane + 64]), 0.0f);

  // ---- FC3 ----
  FC_LAYER(fl3, 0)
  out[(b * NOUT + lane) * NP + p] = h0 + b3[lane];            // lane < 97 always
  if (lane < NOUT - 64)
    out[(b * NOUT + lane + 64) * NP + p] = h1 + b3[lane + 64];
}

extern "C" void kernel_launch(void* const* d_in, const int* in_sizes, int n_in,
                              void* d_out, int out_size, void* d_ws, size_t ws_size,
                              hipStream_t stream) {
  const float* xyz      = (const float*)d_in[0];
  const float* features = (const float*)d_in[1];
  const float* sa_w0 = (const float*)d_in[2];
  const float* sa_s0 = (const float*)d_in[3];
  const float* sa_t0 = (const float*)d_in[4];
  const float* sa_w1 = (const float*)d_in[5];
  const float* sa_s1 = (const float*)d_in[6];
  const float* sa_t1 = (const float*)d_in[7];
  const float* sa_w2 = (const float*)d_in[8];
  const float* sa_s2 = (const float*)d_in[9];
  const float* sa_t2 = (const float*)d_in[10];
  const float* fc_w1 = (const float*)d_in[11];
  const float* fc_s1 = (const float*)d_in[12];
  const float* fc_t1 = (const float*)d_in[13];
  const float* fc_w2 = (const float*)d_in[14];
  const float* fc_s2 = (const float*)d_in[15];
  const float* fc_t2 = (const float*)d_in[16];
  const float* fc_w3 = (const float*)d_in[17];
  const float* fc_b3 = (const float*)d_in[18];
  float* out = (float*)d_out;

  char* ws = (char*)d_ws;
  int* inds = (int*)ws;            ws += (size_t)NB * NP * sizeof(int);
  float* w0l  = (float*)ws;        ws += (size_t)256 * 128 * sizeof(float);
  float* w0x  = (float*)ws;        ws += (size_t)3 * 128 * sizeof(float);
  float* wl1  = (float*)ws;        ws += (size_t)128 * 128 * sizeof(float);
  float* wl2  = (float*)ws;        ws += (size_t)128 * 128 * sizeof(float);
  float* fl1  = (float*)ws;        ws += (size_t)128 * 128 * sizeof(float);
  float* fl2  = (float*)ws;        ws += (size_t)128 * 128 * sizeof(float);
  float* fl3  = (float*)ws;        ws += (size_t)128 * 128 * sizeof(float);
  float* G    = (float*)ws;        ws += (size_t)NB * NPTS * NH * sizeof(float);

  prep_kernel<<<128, 256, 0, stream>>>(sa_w0, sa_w1, sa_w2, fc_w1, fc_w2, fc_w3,
                                       w0l, w0x, wl1, wl2, fl1, fl2, fl3);
  fused_fps_gfeat_kernel<<<NB + NB * (NPTS / 16), 64, 0, stream>>>(
      xyz, inds, features, w0l, G);
  main_kernel<<<NB * NP / 8, 512, 0, stream>>>(
      xyz, inds, G,
      w0x, sa_s0, sa_t0,
      wl1, sa_s1, sa_t1,
      wl2, sa_s2, sa_t2,
      fl1, fc_s1, fc_t1,
      fl2, fc_s2, fc_t2,
      fl3, fc_b3, out);
}